// Round 7
// baseline (1096.131 us; speedup 1.0000x reference)
//
#include <hip/hip_runtime.h>

#define MAXDEG 64
#define BINSHIFT 10
#define SUBQ 4
#define CAP4 5632   // per (bin,quarter) capacity; mean 4082, sd 64 -> +24 sigma

typedef __bf16 bf16x8 __attribute__((ext_vector_type(8)));
typedef float f32x4 __attribute__((ext_vector_type(4)));

__device__ inline ushort f2bf(float f) {
    unsigned u = __builtin_bit_cast(unsigned, f);
    return (ushort)((u + 0x7fffu + ((u >> 16) & 1u)) >> 16);
}
__device__ inline float bf2f(ushort h) {
    unsigned u = ((unsigned)h) << 16;
    return __builtin_bit_cast(float, u);
}

// split 8 contiguous f32 into hi/lo bf16 fragments (in-register)
__device__ inline void split8(const float* __restrict__ p, bf16x8& hi, bf16x8& lo) {
    float4 v0 = *(const float4*)p;
    float4 v1 = *(const float4*)(p + 4);
    float f[8] = {v0.x, v0.y, v0.z, v0.w, v1.x, v1.y, v1.z, v1.w};
    #pragma unroll
    for (int j = 0; j < 8; ++j) {
        __bf16 h = (__bf16)f[j];
        hi[j] = h;
        lo[j] = (__bf16)(f[j] - (float)h);
    }
}

// ---------------------------------------------------------------------------
// Phase 1: bin edges by dst>>BINSHIFT. Concurrent atomicAdd hands out
// consecutive slots -> payload writes cluster into full cache lines.
// ---------------------------------------------------------------------------
__global__ __launch_bounds__(256) void bin_edges(
    const int* __restrict__ src, const int* __restrict__ dst,
    int* __restrict__ bincnt, uint2* __restrict__ binbuf, int E)
{
    int e = blockIdx.x * 256 + threadIdx.x;
    if (e >= E) return;
    int d = dst[e];
    int b = d >> BINSHIFT;
    int q = e & (SUBQ - 1);
    int slot = atomicAdd(&bincnt[b * SUBQ + q], 1);
    if (slot < CAP4)
        binbuf[((size_t)b * SUBQ + q) * CAP4 + slot] = make_uint2((unsigned)src[e], (unsigned)d);
}

// ---------------------------------------------------------------------------
// Phase 2: drain bins -> padded buckets. col writes land in a 256KB
// per-bin window (L2-resident until lines fill).
// ---------------------------------------------------------------------------
__global__ __launch_bounds__(256) void fill_buckets(
    const int* __restrict__ bincnt, const uint2* __restrict__ binbuf,
    int* __restrict__ deg, int* __restrict__ col)
{
    int b = blockIdx.x >> 2;
    int q = blockIdx.x & 3;
    int cnt = bincnt[b * SUBQ + q];
    cnt = cnt < CAP4 ? cnt : CAP4;
    const uint2* seg = binbuf + ((size_t)b * SUBQ + q) * CAP4;
    for (int i = threadIdx.x; i < cnt; i += 256) {
        uint2 e = seg[i];
        int slot = atomicAdd(&deg[e.y], 1);
        if (slot < MAXDEG) col[(size_t)e.y * MAXDEG + slot] = (int)e.x;
    }
}

// ---------------------------------------------------------------------------
// Weight transpose+split: T[n][k] = split(W[k][n]).
// ---------------------------------------------------------------------------
__global__ __launch_bounds__(256) void wsplit(
    const float* __restrict__ W, ushort* __restrict__ Thi, ushort* __restrict__ Tlo,
    int K, int N)
{
    int idx = blockIdx.x * 256 + threadIdx.x;
    if (idx >= K * N) return;
    int n = idx / K, k = idx % K;
    float v = W[(size_t)k * N + n];
    ushort h = f2bf(v);
    Thi[idx] = h;
    Tlo[idx] = f2bf(v - bf2f(h));
}

__global__ void make_bcat(const float* __restrict__ b2, float* __restrict__ bcat) {
    int t = threadIdx.x;
    bcat[t] = t < 128 ? 0.f : b2[t - 128];
}

__global__ __launch_bounds__(256) void init_logits(
    const float* __restrict__ bc2, float* __restrict__ out, int M)
{
    int n = blockIdx.x * 256 + threadIdx.x;
    if (n < M) *(float2*)(out + (size_t)n * 2) = make_float2(bc2[0], bc2[1]);
}

// x (f32) -> bf16 copy for the L2/L3-resident gather
__global__ __launch_bounds__(256) void xtobf(
    const float* __restrict__ X, ushort* __restrict__ Xb, int n4)
{
    int i = blockIdx.x * 256 + threadIdx.x;
    if (i >= n4) return;
    float4 v = *(const float4*)(X + (size_t)i * 4);
    *(ushort4*)(Xb + (size_t)i * 4) =
        make_ushort4(f2bf(v.x), f2bf(v.y), f2bf(v.z), f2bf(v.w));
}

// ---------------------------------------------------------------------------
// Mean-aggregate (C=128) from bf16 rows -> f32 out. One wave per node.
// ---------------------------------------------------------------------------
__global__ __launch_bounds__(256) void agg_mean_bf16(
    const ushort* __restrict__ Xb, const int* __restrict__ col,
    const int* __restrict__ deg, float* __restrict__ out, int N)
{
    int gw = (blockIdx.x * 256 + threadIdx.x) >> 6;
    if (gw >= N) return;
    int lane = threadIdx.x & 63;
    int d = deg[gw];
    int dc = d < MAXDEG ? d : MAXDEG;
    const int* cl = col + (size_t)gw * MAXDEG;
    float a0 = 0.f, a1 = 0.f;
    int i = 0;
    for (; i + 4 <= dc; i += 4) {
        int4 id4 = *(const int4*)(cl + i);
        ushort2 v0 = *(const ushort2*)(Xb + (size_t)id4.x * 128 + lane * 2);
        ushort2 v1 = *(const ushort2*)(Xb + (size_t)id4.y * 128 + lane * 2);
        ushort2 v2 = *(const ushort2*)(Xb + (size_t)id4.z * 128 + lane * 2);
        ushort2 v3 = *(const ushort2*)(Xb + (size_t)id4.w * 128 + lane * 2);
        a0 += (bf2f(v0.x) + bf2f(v1.x)) + (bf2f(v2.x) + bf2f(v3.x));
        a1 += (bf2f(v0.y) + bf2f(v1.y)) + (bf2f(v2.y) + bf2f(v3.y));
    }
    for (; i < dc; ++i) {
        ushort2 v = *(const ushort2*)(Xb + (size_t)cl[i] * 128 + lane * 2);
        a0 += bf2f(v.x); a1 += bf2f(v.y);
    }
    float inv = 1.0f / (float)(d > 1 ? d : 1);
    *(float2*)(out + (size_t)gw * 128 + lane * 2) = make_float2(a0 * inv, a1 * inv);
}

// ---------------------------------------------------------------------------
// agg_finish: h2[n][c] = mean_{s in nbr(n)} tcat[s][c] + tcat[n][128+c]
// ---------------------------------------------------------------------------
__global__ __launch_bounds__(256) void agg_finish(
    const float* __restrict__ tcat, const int* __restrict__ col,
    const int* __restrict__ deg, float* __restrict__ h2, int N)
{
    int gw = (blockIdx.x * 256 + threadIdx.x) >> 6;
    if (gw >= N) return;
    int lane = threadIdx.x & 63;
    int d = deg[gw];
    int dc = d < MAXDEG ? d : MAXDEG;
    const int* cl = col + (size_t)gw * MAXDEG;
    float a0 = 0.f, a1 = 0.f;
    int i = 0;
    for (; i + 4 <= dc; i += 4) {
        int4 id4 = *(const int4*)(cl + i);
        float2 v0 = *(const float2*)(tcat + (size_t)id4.x * 256 + lane * 2);
        float2 v1 = *(const float2*)(tcat + (size_t)id4.y * 256 + lane * 2);
        float2 v2 = *(const float2*)(tcat + (size_t)id4.z * 256 + lane * 2);
        float2 v3 = *(const float2*)(tcat + (size_t)id4.w * 256 + lane * 2);
        a0 += (v0.x + v1.x) + (v2.x + v3.x);
        a1 += (v0.y + v1.y) + (v2.y + v3.y);
    }
    for (; i < dc; ++i) {
        float2 v = *(const float2*)(tcat + (size_t)cl[i] * 256 + lane * 2);
        a0 += v.x; a1 += v.y;
    }
    float inv = 1.0f / (float)(d > 1 ? d : 1);
    float2 hp = *(const float2*)(tcat + (size_t)gw * 256 + 128 + lane * 2);
    *(float2*)(h2 + (size_t)gw * 128 + lane * 2) =
        make_float2(a0 * inv + hp.x, a1 * inv + hp.y);
}

// ---------------------------------------------------------------------------
// LDS-staged split-bf16 MFMA GEMM, BM=256, BN=256(full), BK=32.
// 512 threads = 8 waves (4M x 2N), wave tile 64x128 (4mi x 8nj of 16x16).
// A f32 [M][K] split hi/lo in-register during staging; B pre-split [256][K].
// Each k-tile staged ONCE, reused by 3 passes: Ahi*Bhi + Alo*Bhi + Ahi*Blo.
// LDS rows padded to 40 ushorts (80B) -> conflict-free reads/writes.
// MODE 0: out[M][256] = act(acc + bias).  MODE 1: fused classifier:
//   logits partial = relu(acc + bias) . (sw0|sw1), shfl-reduced, atomicAdd.
// ---------------------------------------------------------------------------
template<int K, int NPH, int MODE>
__global__ __launch_bounds__(512, 2) void gemm_tile(
    const float* __restrict__ A1, const float* __restrict__ A2,
    const ushort* __restrict__ B1hi, const ushort* __restrict__ B1lo,
    const ushort* __restrict__ B2hi, const ushort* __restrict__ B2lo,
    const float* __restrict__ bias,
    const float* __restrict__ Wc2, float* __restrict__ out, int M, int relu)
{
    __shared__ __align__(16) ushort Ah[256 * 40];
    __shared__ __align__(16) ushort Al[256 * 40];
    __shared__ __align__(16) ushort BhS[256 * 40];
    __shared__ __align__(16) ushort BlS[256 * 40];
    __shared__ float sw0[256], sw1[256];

    const int t = threadIdx.x;
    if constexpr (MODE == 1) {
        if (t < 256) {
            sw0[t] = Wc2[t * 2 + 0];
            sw1[t] = Wc2[t * 2 + 1];
        }
    }

    const int m0 = blockIdx.x * 256;
    const int l  = t & 63;
    const int wv = t >> 6;
    const int wr = (wv >> 1) * 64;     // wave row base (0..192)
    const int wc = (wv & 1) * 128;     // wave col base (0 or 128)
    const int lr = l & 15;
    const int kb = l >> 4;

    const int sr = t >> 1;             // staging row 0..255
    const int sh = t & 1;              // staging k-half

    f32x4 acc[4][8] = {};

    #pragma unroll
    for (int ph = 0; ph < NPH; ++ph) {
        const float*  A  = ph ? A2 : A1;
        const ushort* Bh = ph ? B2hi : B1hi;
        const ushort* Bl = ph ? B2lo : B1lo;
        for (int k0 = 0; k0 < K; k0 += 32) {
            __syncthreads();
            // stage A (f32 -> hi/lo) : 256 rows x 32 k
            {
                int rg = m0 + sr;
                rg = rg < M ? rg : M - 1;
                const float* p = A + (size_t)rg * K + k0 + sh * 16;
                bf16x8 h0, l0, h1, l1;
                split8(p, h0, l0);
                split8(p + 8, h1, l1);
                int base = sr * 40 + sh * 16;
                *(bf16x8*)&Ah[base]     = h0;
                *(bf16x8*)&Ah[base + 8] = h1;
                *(bf16x8*)&Al[base]     = l0;
                *(bf16x8*)&Al[base + 8] = l1;
            }
            // stage B (pre-split) : 256 rows x 32 k
            {
                const ushort* ph_ = Bh + (size_t)sr * K + k0 + sh * 16;
                const ushort* pl_ = Bl + (size_t)sr * K + k0 + sh * 16;
                int base = sr * 40 + sh * 16;
                *(uint4*)&BhS[base]     = *(const uint4*)ph_;
                *(uint4*)&BhS[base + 8] = *(const uint4*)(ph_ + 8);
                *(uint4*)&BlS[base]     = *(const uint4*)pl_;
                *(uint4*)&BlS[base + 8] = *(const uint4*)(pl_ + 8);
            }
            __syncthreads();
            // compute: hoist A frags, loop nj
            bf16x8 ah[4], al_[4];
            #pragma unroll
            for (int mi = 0; mi < 4; ++mi) {
                int off = (wr + mi * 16 + lr) * 40 + kb * 8;
                ah[mi]  = *(const bf16x8*)&Ah[off];
                al_[mi] = *(const bf16x8*)&Al[off];
            }
            #pragma unroll
            for (int nj = 0; nj < 8; ++nj) {
                int off = (wc + nj * 16 + lr) * 40 + kb * 8;
                bf16x8 bh = *(const bf16x8*)&BhS[off];
                bf16x8 bl = *(const bf16x8*)&BlS[off];
                #pragma unroll
                for (int mi = 0; mi < 4; ++mi) {
                    acc[mi][nj] = __builtin_amdgcn_mfma_f32_16x16x32_bf16(ah[mi],  bh, acc[mi][nj], 0, 0, 0);
                    acc[mi][nj] = __builtin_amdgcn_mfma_f32_16x16x32_bf16(al_[mi], bh, acc[mi][nj], 0, 0, 0);
                    acc[mi][nj] = __builtin_amdgcn_mfma_f32_16x16x32_bf16(ah[mi],  bl, acc[mi][nj], 0, 0, 0);
                }
            }
        }
    }

    // D map: col = l&15, row = (l>>4)*4 + reg
    if constexpr (MODE == 0) {
        #pragma unroll
        for (int nj = 0; nj < 8; ++nj) {
            int colg = wc + nj * 16 + lr;
            float bv = bias[colg];
            #pragma unroll
            for (int mi = 0; mi < 4; ++mi) {
                #pragma unroll
                for (int reg = 0; reg < 4; ++reg) {
                    int rowg = m0 + wr + mi * 16 + kb * 4 + reg;
                    if (rowg >= M) continue;
                    float v = acc[mi][nj][reg] + bv;
                    if (relu) v = fmaxf(v, 0.f);
                    out[(size_t)rowg * 256 + colg] = v;
                }
            }
        }
    } else {
        #pragma unroll
        for (int mi = 0; mi < 4; ++mi) {
            #pragma unroll
            for (int reg = 0; reg < 4; ++reg) {
                float s0 = 0.f, s1 = 0.f;
                #pragma unroll
                for (int nj = 0; nj < 8; ++nj) {
                    int colg = wc + nj * 16 + lr;
                    float v = fmaxf(acc[mi][nj][reg] + bias[colg], 0.f);
                    s0 += v * sw0[colg];
                    s1 += v * sw1[colg];
                }
                #pragma unroll
                for (int mk = 1; mk < 16; mk <<= 1) {
                    s0 += __shfl_xor(s0, mk);
                    s1 += __shfl_xor(s1, mk);
                }
                int rowg = m0 + wr + mi * 16 + kb * 4 + reg;
                if (lr == 0 && rowg < M) {
                    atomicAdd(&out[(size_t)rowg * 2 + 0], s0);
                    atomicAdd(&out[(size_t)rowg * 2 + 1], s1);
                }
            }
        }
    }
}

// ---------------------------------------------------------------------------
extern "C" void kernel_launch(void* const* d_in, const int* in_sizes, int n_in,
                              void* d_out, int out_size, void* d_ws, size_t ws_size,
                              hipStream_t stream)
{
    const float* x   = (const float*)d_in[0];
    const int*   ei  = (const int*)d_in[1];
    const float* Wl1 = (const float*)d_in[2];
    const float* Wr1 = (const float*)d_in[3];
    const float* b1  = (const float*)d_in[4];
    const float* Wl2 = (const float*)d_in[5];
    const float* Wr2 = (const float*)d_in[6];
    const float* b2  = (const float*)d_in[7];
    const float* Wc1 = (const float*)d_in[8];
    const float* bc1 = (const float*)d_in[9];
    const float* Wc2 = (const float*)d_in[10];
    const float* bc2 = (const float*)d_in[11];

    const int N = in_sizes[0] / 128;   // 100000
    const int E = in_sizes[1] / 2;     // 1600000
    const int nbins = (N + (1 << BINSHIFT) - 1) >> BINSHIFT;   // 98

    char* ws = (char*)d_ws;
    size_t off = 0;
    auto alloc = [&](size_t bytes) -> void* {
        void* p = ws + off;
        off += (bytes + 255) & ~(size_t)255;
        return p;
    };
    const size_t NE128 = (size_t)N * 128;
    const size_t NE256 = (size_t)N * 256;

    int*    deg  = (int*)alloc((size_t)N * 4 + (size_t)nbins * SUBQ * 4);  // deg + bincnt (one memset)
    int*    bincnt = deg + N;
    int*    colb = (int*)alloc((size_t)N * MAXDEG * 4);
    float*  bufA = (float*)alloc(NE256 * 4);   // binbuf -> a1 [N][128] -> tcat [N][256]
    float*  h1   = (float*)alloc(NE256 * 4);   // xb (bf16, dead before h1 written) -> h1 [N][256]
    ushort* wl1h = (ushort*)alloc(256 * 128 * 2); ushort* wl1l = (ushort*)alloc(256 * 128 * 2);
    ushort* wr1h = (ushort*)alloc(256 * 128 * 2); ushort* wr1l = (ushort*)alloc(256 * 128 * 2);
    ushort* w2h  = (ushort*)alloc(256 * 256 * 2); ushort* w2l  = (ushort*)alloc(256 * 256 * 2);
    ushort* wc1h = (ushort*)alloc(256 * 128 * 2); ushort* wc1l = (ushort*)alloc(256 * 128 * 2);
    float*  bcat = (float*)alloc(256 * 4);

    uint2*  binbuf = (uint2*)bufA;     // 98*4*5632*8B = 17.7MB, dead before a1 written
    float*  a1   = bufA;               // [N][128]
    float*  tcat = bufA;               // [N][256] = [t2 | h2p]  (a1 dead by then)
    ushort* xb   = (ushort*)h1;        // bf16 x copy, ALIASED into h1 slab (dead before gemm1)

    float* h2     = (float*)d_out;                   // [N][128]  (output 0)
    float* logits = (float*)d_out + NE128;           // [N][2]    (output 1)

    const int gm = (N + 255) / 256;                  // 391

    hipMemsetAsync(deg, 0, (size_t)N * 4 + (size_t)nbins * SUBQ * 4, stream);

    // two-phase bucket build
    bin_edges<<<dim3((E + 255) / 256), dim3(256), 0, stream>>>(ei, ei + E, bincnt, binbuf, E);
    fill_buckets<<<dim3(nbins * SUBQ), dim3(256), 0, stream>>>(bincnt, binbuf, deg, colb);

    // prep (tiny + one pass over x)
    xtobf<<<dim3((int)(NE128 / 4 + 255) / 256), dim3(256), 0, stream>>>(x, xb, (int)(NE128 / 4));
    wsplit<<<dim3(128), dim3(256), 0, stream>>>(Wl1, wl1h, wl1l, 128, 256);
    wsplit<<<dim3(128), dim3(256), 0, stream>>>(Wr1, wr1h, wr1l, 128, 256);
    wsplit<<<dim3(128), dim3(256), 0, stream>>>(Wl2, w2h, w2l, 256, 128);
    wsplit<<<dim3(128), dim3(256), 0, stream>>>(Wr2, w2h + 128 * 256, w2l + 128 * 256, 256, 128);
    wsplit<<<dim3(128), dim3(256), 0, stream>>>(Wc1, wc1h, wc1l, 128, 256);
    make_bcat<<<dim3(1), dim3(256), 0, stream>>>(b2, bcat);
    init_logits<<<dim3((N + 255) / 256), dim3(256), 0, stream>>>(bc2, logits, N);

    // Layer 1: h1 = relu(mean(x)@Wl1 + x@Wr1 + b1)   [N][256]
    agg_mean_bf16<<<dim3((N + 3) / 4), dim3(256), 0, stream>>>(xb, colb, deg, a1, N);
    gemm_tile<128, 2, 0><<<dim3(gm), dim3(512), 0, stream>>>(
        a1, x, wl1h, wl1l, wr1h, wr1l, b1, nullptr, h1, N, 1);

    // Layer 2 fused: tcat = [h1@Wl2 | h1@Wr2 + b2]   [N][256]
    gemm_tile<256, 1, 0><<<dim3(gm), dim3(512), 0, stream>>>(
        h1, nullptr, w2h, w2l, nullptr, nullptr, bcat, nullptr, tcat, N, 0);

    // h2 = mean(t2) + h2p  -> d_out
    agg_finish<<<dim3((N + 3) / 4), dim3(256), 0, stream>>>(tcat, colb, deg, h2, N);

    // Classifier fused: logits += relu(h2@Wc1 + bc1) @ Wc2   (bc2 pre-init)
    gemm_tile<128, 1, 1><<<dim3(gm), dim3(512), 0, stream>>>(
        h2, nullptr, wc1h, wc1l, nullptr, nullptr, bc1, Wc2, logits, N, 1);
}

// Round 8
// 496.678 us; speedup vs baseline: 2.2069x; 2.2069x over previous
//
#include <hip/hip_runtime.h>

#define MAXDEG 64
#define BINSHIFT 10
#define CAP 20480        // per-bin capacity; mean 16326, +32 sigma
#define CHUNK 4096       // edges per bin_edges block

typedef __bf16 bf16x8 __attribute__((ext_vector_type(8)));
typedef float f32x4 __attribute__((ext_vector_type(4)));

__device__ inline ushort f2bf(float f) {
    unsigned u = __builtin_bit_cast(unsigned, f);
    return (ushort)((u + 0x7fffu + ((u >> 16) & 1u)) >> 16);
}
__device__ inline float bf2f(ushort h) {
    unsigned u = ((unsigned)h) << 16;
    return __builtin_bit_cast(float, u);
}

// split 8 contiguous f32 into hi/lo bf16 fragments (in-register)
__device__ inline void split8(const float* __restrict__ p, bf16x8& hi, bf16x8& lo) {
    float4 v0 = *(const float4*)p;
    float4 v1 = *(const float4*)(p + 4);
    float f[8] = {v0.x, v0.y, v0.z, v0.w, v1.x, v1.y, v1.z, v1.w};
    #pragma unroll
    for (int j = 0; j < 8; ++j) {
        __bf16 h = (__bf16)f[j];
        hi[j] = h;
        lo[j] = (__bf16)(f[j] - (float)h);
    }
}

// ---------------------------------------------------------------------------
// Phase 1: block-local LDS histogram -> one range-reservation atomic per
// (block,bin) -> contiguous runs written to binbuf. 38K global atomics total.
// ---------------------------------------------------------------------------
__global__ __launch_bounds__(256) void bin_edges(
    const int* __restrict__ src, const int* __restrict__ dst,
    int* __restrict__ bincnt, uint2* __restrict__ binbuf, int E)
{
    __shared__ int hist[128];
    __shared__ int base[128];
    const int t = threadIdx.x;
    if (t < 128) hist[t] = 0;
    __syncthreads();

    const int e0 = blockIdx.x * CHUNK;
    int s[16], d[16], sl[16];
    #pragma unroll
    for (int j = 0; j < 16; ++j) {
        int e = e0 + j * 256 + t;
        if (e < E) {
            s[j]  = src[e];
            d[j]  = dst[e];
            sl[j] = atomicAdd(&hist[d[j] >> BINSHIFT], 1);
        } else {
            d[j] = -1;
        }
    }
    __syncthreads();
    if (t < 128 && hist[t] > 0) base[t] = atomicAdd(&bincnt[t], hist[t]);
    __syncthreads();
    #pragma unroll
    for (int j = 0; j < 16; ++j) {
        if (d[j] >= 0) {
            int b = d[j] >> BINSHIFT;
            int pos = base[b] + sl[j];
            if (pos < CAP)
                binbuf[(size_t)b * CAP + pos] = make_uint2((unsigned)s[j], (unsigned)d[j]);
        }
    }
}

// ---------------------------------------------------------------------------
// Phase 2: one block per bin. deg counting in LDS; col writes confined to a
// 256KB single-XCD window -> full-line writebacks. deg written once (no memset).
// ---------------------------------------------------------------------------
__global__ __launch_bounds__(512) void fill_buckets(
    const int* __restrict__ bincnt, const uint2* __restrict__ binbuf,
    int* __restrict__ deg, int* __restrict__ col, int N)
{
    __shared__ int ldeg[1024];
    const int b = blockIdx.x;
    const int t = threadIdx.x;
    ldeg[t] = 0;
    ldeg[t + 512] = 0;
    __syncthreads();
    int cnt = bincnt[b];
    cnt = cnt < CAP ? cnt : CAP;
    const uint2* seg = binbuf + (size_t)b * CAP;
    for (int i = t; i < cnt; i += 512) {
        uint2 e = seg[i];
        int slot = atomicAdd(&ldeg[e.y & 1023], 1);
        if (slot < MAXDEG) col[(size_t)e.y * MAXDEG + slot] = (int)e.x;
    }
    __syncthreads();
    int nb = b << BINSHIFT;
    #pragma unroll
    for (int u = 0; u < 2; ++u) {
        int i = t + u * 512;
        int node = nb + i;
        if (node < N) deg[node] = ldeg[i];
    }
}

// ---------------------------------------------------------------------------
// Weight transpose+split: T[n][k] = split(W[k][n]).
// ---------------------------------------------------------------------------
__global__ __launch_bounds__(256) void wsplit(
    const float* __restrict__ W, ushort* __restrict__ Thi, ushort* __restrict__ Tlo,
    int K, int N)
{
    int idx = blockIdx.x * 256 + threadIdx.x;
    if (idx >= K * N) return;
    int n = idx / K, k = idx % K;
    float v = W[(size_t)k * N + n];
    ushort h = f2bf(v);
    Thi[idx] = h;
    Tlo[idx] = f2bf(v - bf2f(h));
}

__global__ void make_bcat(const float* __restrict__ b2, float* __restrict__ bcat) {
    int t = threadIdx.x;
    bcat[t] = t < 128 ? 0.f : b2[t - 128];
}

__global__ __launch_bounds__(256) void init_logits(
    const float* __restrict__ bc2, float* __restrict__ out, int M)
{
    int n = blockIdx.x * 256 + threadIdx.x;
    if (n < M) *(float2*)(out + (size_t)n * 2) = make_float2(bc2[0], bc2[1]);
}

// x (f32) -> bf16 copy for the L2/L3-resident gather
__global__ __launch_bounds__(256) void xtobf(
    const float* __restrict__ X, ushort* __restrict__ Xb, int n4)
{
    int i = blockIdx.x * 256 + threadIdx.x;
    if (i >= n4) return;
    float4 v = *(const float4*)(X + (size_t)i * 4);
    *(ushort4*)(Xb + (size_t)i * 4) =
        make_ushort4(f2bf(v.x), f2bf(v.y), f2bf(v.z), f2bf(v.w));
}

// ---------------------------------------------------------------------------
// Mean-aggregate (C=128) from bf16 rows -> f32 out. One wave per node.
// ---------------------------------------------------------------------------
__global__ __launch_bounds__(256) void agg_mean_bf16(
    const ushort* __restrict__ Xb, const int* __restrict__ col,
    const int* __restrict__ deg, float* __restrict__ out, int N)
{
    int gw = (blockIdx.x * 256 + threadIdx.x) >> 6;
    if (gw >= N) return;
    int lane = threadIdx.x & 63;
    int d = deg[gw];
    int dc = d < MAXDEG ? d : MAXDEG;
    const int* cl = col + (size_t)gw * MAXDEG;
    float a0 = 0.f, a1 = 0.f;
    int i = 0;
    for (; i + 4 <= dc; i += 4) {
        int4 id4 = *(const int4*)(cl + i);
        ushort2 v0 = *(const ushort2*)(Xb + (size_t)id4.x * 128 + lane * 2);
        ushort2 v1 = *(const ushort2*)(Xb + (size_t)id4.y * 128 + lane * 2);
        ushort2 v2 = *(const ushort2*)(Xb + (size_t)id4.z * 128 + lane * 2);
        ushort2 v3 = *(const ushort2*)(Xb + (size_t)id4.w * 128 + lane * 2);
        a0 += (bf2f(v0.x) + bf2f(v1.x)) + (bf2f(v2.x) + bf2f(v3.x));
        a1 += (bf2f(v0.y) + bf2f(v1.y)) + (bf2f(v2.y) + bf2f(v3.y));
    }
    for (; i < dc; ++i) {
        ushort2 v = *(const ushort2*)(Xb + (size_t)cl[i] * 128 + lane * 2);
        a0 += bf2f(v.x); a1 += bf2f(v.y);
    }
    float inv = 1.0f / (float)(d > 1 ? d : 1);
    *(float2*)(out + (size_t)gw * 128 + lane * 2) = make_float2(a0 * inv, a1 * inv);
}

// ---------------------------------------------------------------------------
// agg_finish: h2[n][c] = mean_{s in nbr(n)} tcat[s][c] + tcat[n][128+c]
// ---------------------------------------------------------------------------
__global__ __launch_bounds__(256) void agg_finish(
    const float* __restrict__ tcat, const int* __restrict__ col,
    const int* __restrict__ deg, float* __restrict__ h2, int N)
{
    int gw = (blockIdx.x * 256 + threadIdx.x) >> 6;
    if (gw >= N) return;
    int lane = threadIdx.x & 63;
    int d = deg[gw];
    int dc = d < MAXDEG ? d : MAXDEG;
    const int* cl = col + (size_t)gw * MAXDEG;
    float a0 = 0.f, a1 = 0.f;
    int i = 0;
    for (; i + 4 <= dc; i += 4) {
        int4 id4 = *(const int4*)(cl + i);
        float2 v0 = *(const float2*)(tcat + (size_t)id4.x * 256 + lane * 2);
        float2 v1 = *(const float2*)(tcat + (size_t)id4.y * 256 + lane * 2);
        float2 v2 = *(const float2*)(tcat + (size_t)id4.z * 256 + lane * 2);
        float2 v3 = *(const float2*)(tcat + (size_t)id4.w * 256 + lane * 2);
        a0 += (v0.x + v1.x) + (v2.x + v3.x);
        a1 += (v0.y + v1.y) + (v2.y + v3.y);
    }
    for (; i < dc; ++i) {
        float2 v = *(const float2*)(tcat + (size_t)cl[i] * 256 + lane * 2);
        a0 += v.x; a1 += v.y;
    }
    float inv = 1.0f / (float)(d > 1 ? d : 1);
    float2 hp = *(const float2*)(tcat + (size_t)gw * 256 + 128 + lane * 2);
    *(float2*)(h2 + (size_t)gw * 128 + lane * 2) =
        make_float2(a0 * inv + hp.x, a1 * inv + hp.y);
}

// ---------------------------------------------------------------------------
// LDS-staged split-bf16 MFMA GEMM, BM=256, BN=256(full), BK=32.
// 512 threads = 8 waves (4M x 2N), wave tile 64x128 (4mi x 8nj of 16x16).
// A f32 [M][K] split hi/lo in-register during staging; B pre-split [256][K].
// Each k-tile staged ONCE, reused by 3 passes: Ahi*Bhi + Alo*Bhi + Ahi*Blo.
// LDS rows padded to 40 ushorts (80B) -> conflict-free reads/writes.
// MODE 0: out[M][256] = act(acc + bias).  MODE 1: fused classifier:
//   logits partial = relu(acc + bias) . (sw0|sw1), shfl-reduced, atomicAdd.
// ---------------------------------------------------------------------------
template<int K, int NPH, int MODE>
__global__ __launch_bounds__(512, 2) void gemm_tile(
    const float* __restrict__ A1, const float* __restrict__ A2,
    const ushort* __restrict__ B1hi, const ushort* __restrict__ B1lo,
    const ushort* __restrict__ B2hi, const ushort* __restrict__ B2lo,
    const float* __restrict__ bias,
    const float* __restrict__ Wc2, float* __restrict__ out, int M, int relu)
{
    __shared__ __align__(16) ushort Ah[256 * 40];
    __shared__ __align__(16) ushort Al[256 * 40];
    __shared__ __align__(16) ushort BhS[256 * 40];
    __shared__ __align__(16) ushort BlS[256 * 40];
    __shared__ float sw0[256], sw1[256];

    const int t = threadIdx.x;
    if constexpr (MODE == 1) {
        if (t < 256) {
            sw0[t] = Wc2[t * 2 + 0];
            sw1[t] = Wc2[t * 2 + 1];
        }
    }

    const int m0 = blockIdx.x * 256;
    const int l  = t & 63;
    const int wv = t >> 6;
    const int wr = (wv >> 1) * 64;     // wave row base (0..192)
    const int wc = (wv & 1) * 128;     // wave col base (0 or 128)
    const int lr = l & 15;
    const int kb = l >> 4;

    const int sr = t >> 1;             // staging row 0..255
    const int sh = t & 1;              // staging k-half

    f32x4 acc[4][8] = {};

    #pragma unroll
    for (int ph = 0; ph < NPH; ++ph) {
        const float*  A  = ph ? A2 : A1;
        const ushort* Bh = ph ? B2hi : B1hi;
        const ushort* Bl = ph ? B2lo : B1lo;
        for (int k0 = 0; k0 < K; k0 += 32) {
            __syncthreads();
            // stage A (f32 -> hi/lo) : 256 rows x 32 k
            {
                int rg = m0 + sr;
                rg = rg < M ? rg : M - 1;
                const float* p = A + (size_t)rg * K + k0 + sh * 16;
                bf16x8 h0, l0, h1, l1;
                split8(p, h0, l0);
                split8(p + 8, h1, l1);
                int base = sr * 40 + sh * 16;
                *(bf16x8*)&Ah[base]     = h0;
                *(bf16x8*)&Ah[base + 8] = h1;
                *(bf16x8*)&Al[base]     = l0;
                *(bf16x8*)&Al[base + 8] = l1;
            }
            // stage B (pre-split) : 256 rows x 32 k
            {
                const ushort* ph_ = Bh + (size_t)sr * K + k0 + sh * 16;
                const ushort* pl_ = Bl + (size_t)sr * K + k0 + sh * 16;
                int base = sr * 40 + sh * 16;
                *(uint4*)&BhS[base]     = *(const uint4*)ph_;
                *(uint4*)&BhS[base + 8] = *(const uint4*)(ph_ + 8);
                *(uint4*)&BlS[base]     = *(const uint4*)pl_;
                *(uint4*)&BlS[base + 8] = *(const uint4*)(pl_ + 8);
            }
            __syncthreads();
            // compute: hoist A frags, loop nj
            bf16x8 ah[4], al_[4];
            #pragma unroll
            for (int mi = 0; mi < 4; ++mi) {
                int off = (wr + mi * 16 + lr) * 40 + kb * 8;
                ah[mi]  = *(const bf16x8*)&Ah[off];
                al_[mi] = *(const bf16x8*)&Al[off];
            }
            #pragma unroll
            for (int nj = 0; nj < 8; ++nj) {
                int off = (wc + nj * 16 + lr) * 40 + kb * 8;
                bf16x8 bh = *(const bf16x8*)&BhS[off];
                bf16x8 bl = *(const bf16x8*)&BlS[off];
                #pragma unroll
                for (int mi = 0; mi < 4; ++mi) {
                    acc[mi][nj] = __builtin_amdgcn_mfma_f32_16x16x32_bf16(ah[mi],  bh, acc[mi][nj], 0, 0, 0);
                    acc[mi][nj] = __builtin_amdgcn_mfma_f32_16x16x32_bf16(al_[mi], bh, acc[mi][nj], 0, 0, 0);
                    acc[mi][nj] = __builtin_amdgcn_mfma_f32_16x16x32_bf16(ah[mi],  bl, acc[mi][nj], 0, 0, 0);
                }
            }
        }
    }

    // D map: col = l&15, row = (l>>4)*4 + reg
    if constexpr (MODE == 0) {
        #pragma unroll
        for (int nj = 0; nj < 8; ++nj) {
            int colg = wc + nj * 16 + lr;
            float bv = bias[colg];
            #pragma unroll
            for (int mi = 0; mi < 4; ++mi) {
                #pragma unroll
                for (int reg = 0; reg < 4; ++reg) {
                    int rowg = m0 + wr + mi * 16 + kb * 4 + reg;
                    if (rowg >= M) continue;
                    float v = acc[mi][nj][reg] + bv;
                    if (relu) v = fmaxf(v, 0.f);
                    out[(size_t)rowg * 256 + colg] = v;
                }
            }
        }
    } else {
        #pragma unroll
        for (int mi = 0; mi < 4; ++mi) {
            #pragma unroll
            for (int reg = 0; reg < 4; ++reg) {
                float s0 = 0.f, s1 = 0.f;
                #pragma unroll
                for (int nj = 0; nj < 8; ++nj) {
                    int colg = wc + nj * 16 + lr;
                    float v = fmaxf(acc[mi][nj][reg] + bias[colg], 0.f);
                    s0 += v * sw0[colg];
                    s1 += v * sw1[colg];
                }
                #pragma unroll
                for (int mk = 1; mk < 16; mk <<= 1) {
                    s0 += __shfl_xor(s0, mk);
                    s1 += __shfl_xor(s1, mk);
                }
                int rowg = m0 + wr + mi * 16 + kb * 4 + reg;
                if (lr == 0 && rowg < M) {
                    atomicAdd(&out[(size_t)rowg * 2 + 0], s0);
                    atomicAdd(&out[(size_t)rowg * 2 + 1], s1);
                }
            }
        }
    }
}

// ---------------------------------------------------------------------------
extern "C" void kernel_launch(void* const* d_in, const int* in_sizes, int n_in,
                              void* d_out, int out_size, void* d_ws, size_t ws_size,
                              hipStream_t stream)
{
    const float* x   = (const float*)d_in[0];
    const int*   ei  = (const int*)d_in[1];
    const float* Wl1 = (const float*)d_in[2];
    const float* Wr1 = (const float*)d_in[3];
    const float* b1  = (const float*)d_in[4];
    const float* Wl2 = (const float*)d_in[5];
    const float* Wr2 = (const float*)d_in[6];
    const float* b2  = (const float*)d_in[7];
    const float* Wc1 = (const float*)d_in[8];
    const float* bc1 = (const float*)d_in[9];
    const float* Wc2 = (const float*)d_in[10];
    const float* bc2 = (const float*)d_in[11];

    const int N = in_sizes[0] / 128;   // 100000
    const int E = in_sizes[1] / 2;     // 1600000
    const int nbins = (N + (1 << BINSHIFT) - 1) >> BINSHIFT;   // 98

    char* ws = (char*)d_ws;
    size_t off = 0;
    auto alloc = [&](size_t bytes) -> void* {
        void* p = ws + off;
        off += (bytes + 255) & ~(size_t)255;
        return p;
    };
    const size_t NE128 = (size_t)N * 128;
    const size_t NE256 = (size_t)N * 256;

    int*    bincnt = (int*)alloc((size_t)nbins * 4);
    int*    deg  = (int*)alloc((size_t)N * 4);
    int*    colb = (int*)alloc((size_t)N * MAXDEG * 4);
    float*  bufA = (float*)alloc(NE256 * 4);   // binbuf -> a1 [N][128] -> tcat [N][256]
    float*  h1   = (float*)alloc(NE256 * 4);   // xb (bf16, dead before h1 written) -> h1 [N][256]
    ushort* wl1h = (ushort*)alloc(256 * 128 * 2); ushort* wl1l = (ushort*)alloc(256 * 128 * 2);
    ushort* wr1h = (ushort*)alloc(256 * 128 * 2); ushort* wr1l = (ushort*)alloc(256 * 128 * 2);
    ushort* w2h  = (ushort*)alloc(256 * 256 * 2); ushort* w2l  = (ushort*)alloc(256 * 256 * 2);
    ushort* wc1h = (ushort*)alloc(256 * 128 * 2); ushort* wc1l = (ushort*)alloc(256 * 128 * 2);
    float*  bcat = (float*)alloc(256 * 4);

    uint2*  binbuf = (uint2*)bufA;     // 98*20480*8B = 16MB, dead before a1 written
    float*  a1   = bufA;               // [N][128]
    float*  tcat = bufA;               // [N][256] = [t2 | h2p]  (a1 dead by then)
    ushort* xb   = (ushort*)h1;        // bf16 x copy, ALIASED into h1 slab (dead before gemm1)

    float* h2     = (float*)d_out;                   // [N][128]  (output 0)
    float* logits = (float*)d_out + NE128;           // [N][2]    (output 1)

    const int gm = (N + 255) / 256;                  // 391

    hipMemsetAsync(bincnt, 0, (size_t)nbins * 4, stream);

    // two-phase bucket build (block-local histogram -> single-XCD bin fill)
    bin_edges<<<dim3((E + CHUNK - 1) / CHUNK), dim3(256), 0, stream>>>(
        ei, ei + E, bincnt, binbuf, E);
    fill_buckets<<<dim3(nbins), dim3(512), 0, stream>>>(bincnt, binbuf, deg, colb, N);

    // prep (tiny + one pass over x)
    xtobf<<<dim3((int)(NE128 / 4 + 255) / 256), dim3(256), 0, stream>>>(x, xb, (int)(NE128 / 4));
    wsplit<<<dim3(128), dim3(256), 0, stream>>>(Wl1, wl1h, wl1l, 128, 256);
    wsplit<<<dim3(128), dim3(256), 0, stream>>>(Wr1, wr1h, wr1l, 128, 256);
    wsplit<<<dim3(128), dim3(256), 0, stream>>>(Wl2, w2h, w2l, 256, 128);
    wsplit<<<dim3(128), dim3(256), 0, stream>>>(Wr2, w2h + 128 * 256, w2l + 128 * 256, 256, 128);
    wsplit<<<dim3(128), dim3(256), 0, stream>>>(Wc1, wc1h, wc1l, 128, 256);
    make_bcat<<<dim3(1), dim3(256), 0, stream>>>(b2, bcat);
    init_logits<<<dim3((N + 255) / 256), dim3(256), 0, stream>>>(bc2, logits, N);

    // Layer 1: h1 = relu(mean(x)@Wl1 + x@Wr1 + b1)   [N][256]
    agg_mean_bf16<<<dim3((N + 3) / 4), dim3(256), 0, stream>>>(xb, colb, deg, a1, N);
    gemm_tile<128, 2, 0><<<dim3(gm), dim3(512), 0, stream>>>(
        a1, x, wl1h, wl1l, wr1h, wr1l, b1, nullptr, h1, N, 1);

    // Layer 2 fused: tcat = [h1@Wl2 | h1@Wr2 + b2]   [N][256]
    gemm_tile<256, 1, 0><<<dim3(gm), dim3(512), 0, stream>>>(
        h1, nullptr, w2h, w2l, nullptr, nullptr, bcat, nullptr, tcat, N, 0);

    // h2 = mean(t2) + h2p  -> d_out
    agg_finish<<<dim3((N + 3) / 4), dim3(256), 0, stream>>>(tcat, colb, deg, h2, N);

    // Classifier fused: logits += relu(h2@Wc1 + bc1) @ Wc2   (bc2 pre-init)
    gemm_tile<128, 1, 1><<<dim3(gm), dim3(512), 0, stream>>>(
        h2, nullptr, wc1h, wc1l, nullptr, nullptr, bc1, Wc2, logits, N, 1);
}